// Round 7
// baseline (3028.980 us; speedup 1.0000x reference)
//
#include <hip/hip_runtime.h>

// TopDownTreeLSTM on MI355X — round 7: round-6 tile-grained dataflow
// + ordering fixes: (1) __syncthreads between D_s scatter and readback
// (cross-lane LDS RAW needs a barrier), (2) sched_barrier(0) after poll,
// (3) threadfence in k_root before publish.

#define NN 32768
#define DD 256

typedef __attribute__((ext_vector_type(8))) short short8;
typedef __attribute__((ext_vector_type(4))) float float4_;

static __device__ __forceinline__ unsigned short f2bf(float f) {
    unsigned u = __builtin_bit_cast(unsigned, f);
    unsigned r = u + 0x7FFFu + ((u >> 16) & 1u);
    return (unsigned short)(r >> 16);
}
static __device__ __forceinline__ float bf2f(unsigned short u) {
    unsigned v = ((unsigned)u) << 16;
    return __builtin_bit_cast(float, v);
}
static __device__ __forceinline__ float sigf(float x) { return 1.0f / (1.0f + __expf(-x)); }
static __device__ __forceinline__ float tanh_(float x) { return 1.0f - 2.0f / (__expf(2.0f * x) + 1.0f); }

__global__ void k_init(int* cnt, int* cur, int* done2) {
    int g = blockIdx.x * 256 + threadIdx.x;
    if (g < NN + 2) { cnt[g] = 0; cur[g] = 0; done2[g] = 0; }
}

__global__ void k_root(const float* __restrict__ X, const float* __restrict__ state,
                       const float* __restrict__ rootW, const float* __restrict__ rootb,
                       const int* __restrict__ idx,
                       unsigned short* __restrict__ Hb, float* __restrict__ C, int* __restrict__ done2) {
    const int t = threadIdx.x;
    const int row = idx[0];
    const float4_* xr = (const float4_*)(X + (size_t)row * DD);
    const float4_* wr = (const float4_*)(rootW + (size_t)t * DD);
    float acc = rootb[t];
    for (int k = 0; k < DD / 4; ++k) {
        float4_ a = xr[k], b = wr[k];
        acc += a[0] * b[0] + a[1] * b[1] + a[2] * b[2] + a[3] * b[3];
    }
    Hb[t] = f2bf(tanh_(acc));
    C[t] = state[t];
    __syncthreads();
    __threadfence();
    if (t == 0) __hip_atomic_store(&done2[0], 8, __ATOMIC_RELEASE, __HIP_MEMORY_SCOPE_AGENT);
}

__global__ void k_dep_init(const int* __restrict__ parents, int* dep, int* jmp) {
    int i = blockIdx.x * 256 + threadIdx.x;
    if (i >= NN) return;
    dep[i] = (i == 0) ? 0 : 1;
    jmp[i] = (i == 0) ? 0 : parents[i];
}

__global__ void k_dep_step(const int* __restrict__ depA, const int* __restrict__ jmpA,
                           int* __restrict__ depB, int* __restrict__ jmpB) {
    int i = blockIdx.x * 256 + threadIdx.x;
    if (i >= NN) return;
    int j = jmpA[i];
    depB[i] = depA[i] + depA[j];
    jmpB[i] = jmpA[j];
}

__global__ void k_hist(const int* __restrict__ dep, int* cnt) {
    int i = blockIdx.x * 256 + threadIdx.x;
    if (i >= NN) return;
    atomicAdd(&cnt[dep[i]], 1);
}

__global__ void k_scan2(const int* __restrict__ cnt, int* __restrict__ off,
                        int* __restrict__ tb, int* __restrict__ nt) {
    __shared__ int sums[256], tsums[256];
    const int tid = threadIdx.x;
    const int base = tid * 128;
    int s = 0, st = 0;
    for (int k = 0; k < 128; ++k) { int c = cnt[base + k]; s += c; st += (c + 15) >> 4; }
    sums[tid] = s; tsums[tid] = st;
    __syncthreads();
    if (tid == 0) {
        int run = 0, trun = 0;
        for (int t = 0; t < 256; ++t) {
            int a = sums[t]; sums[t] = run; run += a;
            int b = tsums[t]; tsums[t] = trun; trun += b;
        }
    }
    __syncthreads();
    int run = sums[tid], trun = tsums[tid];
    for (int k = 0; k < 128; ++k) {
        off[base + k] = run; tb[base + k] = trun;
        run += cnt[base + k]; trun += (cnt[base + k] + 15) >> 4;
    }
    if (tid == 255) { off[NN] = run; tb[NN] = trun; nt[0] = trun; }
}

__global__ void k_scatter2(const int* __restrict__ dep, const int* __restrict__ off,
                           const int* __restrict__ tb, int* cur,
                           int* __restrict__ lev, int* __restrict__ tile_of) {
    int i = blockIdx.x * 256 + threadIdx.x;
    if (i >= NN) return;
    int d = dep[i];
    int pos = off[d] + atomicAdd(&cur[d], 1);
    lev[pos] = i;
    tile_of[i] = tb[d] + ((pos - off[d]) >> 4);
}

__global__ void k_tiles(const int* __restrict__ off, const int* __restrict__ tb,
                        int* __restrict__ tstart, int* __restrict__ tcount) {
    int d = blockIdx.x * 256 + threadIdx.x;
    if (d >= NN) return;
    int lo = off[d], hi = off[d + 1], t0 = tb[d];
    for (int k = 0; 16 * k < hi - lo; ++k) {
        tstart[t0 + k] = lo + 16 * k;
        tcount[t0 + k] = min(16, hi - lo - 16 * k);
    }
}

__global__ __launch_bounds__(256, 1) void k_tree3(
    const float* __restrict__ X, const float* __restrict__ Wih, const float* __restrict__ Whh,
    const float* __restrict__ bih, const float* __restrict__ bhh,
    const int* __restrict__ parents, const int* __restrict__ idx,
    const int* __restrict__ tstart, const int* __restrict__ tcount,
    const int* __restrict__ nt_g, const int* __restrict__ tile_of,
    const int* __restrict__ lev,
    unsigned short* __restrict__ Hb, float* __restrict__ C, int* __restrict__ done2) {

    __shared__ __align__(16) short w_s[128 * 520];        // [128 rows][x256|h256 +8 pad]
    __shared__ __align__(16) float D_s[4 * 4 * 8 * 16];   // [wave][gate][cc][m]

    const int tid = threadIdx.x;
    const int j = blockIdx.x >> 5, grp = blockIdx.x & 31;
    const int w = tid >> 6, l = tid & 63;
    const int lanelo = l & 15, quad = l >> 4;

    // Stage [Wih|Whh] slice, permuted rows: rp=(wv,tt,ll) -> gate g=ll>>2,
    // cc=tt*4+(ll&3), global gate-row G = g*256 + j*32 + wv*8 + cc.
    for (int e = tid; e < 128 * 64; e += 256) {
        int rp = e >> 6, c4 = (e & 63) * 4;
        int wv = rp >> 5, tt = (rp >> 4) & 1, ll = rp & 15;
        int G = (ll >> 2) * 256 + j * 32 + wv * 8 + tt * 4 + (ll & 3);
        float4_ a = *(const float4_*)(Wih + (size_t)G * DD + c4);
        float4_ b = *(const float4_*)(Whh + (size_t)G * DD + c4);
        unsigned short* pa = (unsigned short*)&w_s[rp * 520 + c4];
        unsigned short* pb = (unsigned short*)&w_s[rp * 520 + 256 + c4];
        pa[0] = f2bf(a[0]); pa[1] = f2bf(a[1]); pa[2] = f2bf(a[2]); pa[3] = f2bf(a[3]);
        pb[0] = f2bf(b[0]); pb[1] = f2bf(b[1]); pb[2] = f2bf(b[2]); pb[3] = f2bf(b[3]);
    }
    __syncthreads();

    const int cc0 = quad, cc1 = quad + 4;
    float bias0[4], bias1[4];
    #pragma unroll
    for (int g = 0; g < 4; ++g) {
        int G0 = g * 256 + j * 32 + w * 8 + cc0;
        int G1 = g * 256 + j * 32 + w * 8 + cc1;
        bias0[g] = bih[G0] + bhh[G0];
        bias1[g] = bih[G1] + bhh[G1];
    }

    const int NT = nt_g[0];
    for (int t = 1 + grp; t < NT; t += 32) {
        const int base = tstart[t], count = tcount[t];
        int node = -1, par = 0, ptile = 0, xrow = 0;
        if (lanelo < count) {
            node = lev[base + lanelo];
            par = parents[node];
            ptile = tile_of[par];
            xrow = idx[node];
        }
        // Prewait: x-half A fragments (plain cached loads, fp32 -> bf16).
        short8 ax[8];
        #pragma unroll
        for (int ks = 0; ks < 8; ++ks) {
            short8 s = (short8){0, 0, 0, 0, 0, 0, 0, 0};
            if (node >= 0) {
                const float* xp = X + (size_t)xrow * DD + ks * 32 + quad * 8;
                float4_ x0 = *(const float4_*)xp;
                float4_ x1 = *(const float4_*)(xp + 4);
                s[0] = f2bf(x0[0]); s[1] = f2bf(x0[1]); s[2] = f2bf(x0[2]); s[3] = f2bf(x0[3]);
                s[4] = f2bf(x1[0]); s[5] = f2bf(x1[1]); s[6] = f2bf(x1[2]); s[7] = f2bf(x1[3]);
            }
            ax[ks] = s;
        }
        // Poll parent-tile counters (target 8 blocks each).
        {
            int ready = (node < 0);
            while (true) {
                if (!ready)
                    ready = (__hip_atomic_load(&done2[ptile], __ATOMIC_RELAXED,
                                               __HIP_MEMORY_SCOPE_AGENT) >= 8);
                if (__all(ready)) break;
                __builtin_amdgcn_s_sleep(1);
            }
        }
        __builtin_amdgcn_sched_barrier(0);   // pin compile-order: nothing crosses the wait
        __builtin_amdgcn_fence(__ATOMIC_ACQUIRE, "workgroup");
        // Parent C for this lane's two (m, cc) pairs.
        float cp0 = 0.f, cp1 = 0.f;
        if (node >= 0) {
            cp0 = __hip_atomic_load(&C[(size_t)par * DD + j * 32 + w * 8 + cc0],
                                    __ATOMIC_RELAXED, __HIP_MEMORY_SCOPE_AGENT);
            cp1 = __hip_atomic_load(&C[(size_t)par * DD + j * 32 + w * 8 + cc1],
                                    __ATOMIC_RELAXED, __HIP_MEMORY_SCOPE_AGENT);
        }
        // h-half A fragments: coherent 8B loads straight into MFMA layout.
        short8 ah[8];
        const unsigned long long* Hb64 = (const unsigned long long*)Hb;
        #pragma unroll
        for (int ks = 0; ks < 8; ++ks) {
            unsigned long long q0 = 0ull, q1 = 0ull;
            if (node >= 0) {
                size_t b8 = (size_t)par * 64 + ks * 8 + quad * 2;
                q0 = __hip_atomic_load(&Hb64[b8], __ATOMIC_RELAXED, __HIP_MEMORY_SCOPE_AGENT);
                q1 = __hip_atomic_load(&Hb64[b8 + 1], __ATOMIC_RELAXED, __HIP_MEMORY_SCOPE_AGENT);
            }
            union { unsigned long long q[2]; short8 s; } u;
            u.q[0] = q0; u.q[1] = q1;
            ah[ks] = u.s;
        }
        // 32 MFMAs: K=512 = x(256) + h(256), 2 n-tiles per wave.
        float4_ acc[2];
        acc[0] = (float4_){0.f, 0.f, 0.f, 0.f};
        acc[1] = (float4_){0.f, 0.f, 0.f, 0.f};
        #pragma unroll
        for (int tt = 0; tt < 2; ++tt) {
            int row = (w * 2 + tt) * 16 + lanelo;
            #pragma unroll
            for (int ks = 0; ks < 8; ++ks) {
                short8 bf = *(const short8*)&w_s[row * 520 + ks * 32 + quad * 8];
                acc[tt] = __builtin_amdgcn_mfma_f32_16x16x32_bf16(ax[ks], bf, acc[tt], 0, 0, 0);
            }
            #pragma unroll
            for (int ks = 0; ks < 8; ++ks) {
                short8 bf = *(const short8*)&w_s[row * 520 + 256 + ks * 32 + quad * 8];
                acc[tt] = __builtin_amdgcn_mfma_f32_16x16x32_bf16(ah[ks], bf, acc[tt], 0, 0, 0);
            }
        }
        // Scatter D to LDS, then BARRIER (cross-lane RAW needs ordering).
        #pragma unroll
        for (int tt = 0; tt < 2; ++tt) {
            int g = lanelo >> 2, cc = tt * 4 + (lanelo & 3);
            #pragma unroll
            for (int r = 0; r < 4; ++r)
                D_s[((w * 4 + g) * 8 + cc) * 16 + quad * 4 + r] = acc[tt][r];
        }
        __syncthreads();
        // Elementwise LSTM for pairs (m=lanelo, cc0) and (m=lanelo, cc1).
        float ig0 = D_s[((w * 4 + 0) * 8 + cc0) * 16 + lanelo] + bias0[0];
        float fg0 = D_s[((w * 4 + 1) * 8 + cc0) * 16 + lanelo] + bias0[1];
        float gg0 = D_s[((w * 4 + 2) * 8 + cc0) * 16 + lanelo] + bias0[2];
        float og0 = D_s[((w * 4 + 3) * 8 + cc0) * 16 + lanelo] + bias0[3];
        float ig1 = D_s[((w * 4 + 0) * 8 + cc1) * 16 + lanelo] + bias1[0];
        float fg1 = D_s[((w * 4 + 1) * 8 + cc1) * 16 + lanelo] + bias1[1];
        float gg1 = D_s[((w * 4 + 2) * 8 + cc1) * 16 + lanelo] + bias1[2];
        float og1 = D_s[((w * 4 + 3) * 8 + cc1) * 16 + lanelo] + bias1[3];
        float cn0 = sigf(fg0) * cp0 + sigf(ig0) * tanh_(gg0);
        float cn1 = sigf(fg1) * cp1 + sigf(ig1) * tanh_(gg1);
        float hn0 = sigf(og0) * tanh_(cn0);
        float hn1 = sigf(og1) * tanh_(cn1);
        unsigned short h0 = f2bf(hn0), h1 = f2bf(hn1);
        int up0 = __shfl((int)h0, (l + 16) & 63);   // partner: same m, cc+1
        int up1 = __shfl((int)h1, (l + 16) & 63);
        if (node >= 0) {
            int col0 = j * 32 + w * 8 + cc0, col1 = j * 32 + w * 8 + cc1;
            __hip_atomic_store(&C[(size_t)node * DD + col0], cn0,
                               __ATOMIC_RELAXED, __HIP_MEMORY_SCOPE_AGENT);
            __hip_atomic_store(&C[(size_t)node * DD + col1], cn1,
                               __ATOMIC_RELAXED, __HIP_MEMORY_SCOPE_AGENT);
            if ((quad & 1) == 0) {
                unsigned p0 = (unsigned)h0 | (((unsigned)(unsigned short)up0) << 16);
                unsigned p1 = (unsigned)h1 | (((unsigned)(unsigned short)up1) << 16);
                __hip_atomic_store(&((unsigned*)Hb)[(size_t)node * 128 + (col0 >> 1)], p0,
                                   __ATOMIC_RELAXED, __HIP_MEMORY_SCOPE_AGENT);
                __hip_atomic_store(&((unsigned*)Hb)[(size_t)node * 128 + (col1 >> 1)], p1,
                                   __ATOMIC_RELAXED, __HIP_MEMORY_SCOPE_AGENT);
            }
        }
        // Publish: per-thread release (vmcnt drain), block barrier, one add.
        __builtin_amdgcn_fence(__ATOMIC_RELEASE, "workgroup");
        __syncthreads();
        if (tid == 0)
            __hip_atomic_fetch_add(&done2[t], 1, __ATOMIC_RELAXED, __HIP_MEMORY_SCOPE_AGENT);
    }
}

__global__ void k_out(const unsigned short* __restrict__ Hb, const float* __restrict__ C,
                      const int* __restrict__ idx, float* __restrict__ out) {
    const int b = blockIdx.x, t = threadIdx.x;
    if (b < NN) {
        int drow = idx[b];
        out[512 + (size_t)drow * DD + t] = bf2f(Hb[(size_t)b * DD + t]);
    } else {
        out[t] = C[t];
        out[DD + t] = bf2f(Hb[t]);
    }
}

extern "C" void kernel_launch(void* const* d_in, const int* in_sizes, int n_in,
                              void* d_out, int out_size, void* d_ws, size_t ws_size,
                              hipStream_t stream) {
    const float* X     = (const float*)d_in[0];
    const float* state = (const float*)d_in[1];
    const float* rootW = (const float*)d_in[2];
    const float* rootb = (const float*)d_in[3];
    const float* Wih   = (const float*)d_in[4];
    const float* Whh   = (const float*)d_in[5];
    const float* bih   = (const float*)d_in[6];
    const float* bhh   = (const float*)d_in[7];
    const int* parents = (const int*)d_in[8];
    const int* idx     = (const int*)d_in[9];

    float* C           = (float*)d_ws;                               // 32 MiB
    unsigned short* Hb = (unsigned short*)(C + (size_t)NN * DD);     // 16 MiB
    int* ip            = (int*)(Hb + (size_t)NN * DD);
    int* depA    = ip; ip += NN;
    int* jmpA    = ip; ip += NN;
    int* depB    = ip; ip += NN;
    int* jmpB    = ip; ip += NN;
    int* cnt     = ip; ip += NN + 2;
    int* off     = ip; ip += NN + 2;
    int* tb      = ip; ip += NN + 2;
    int* cur     = ip; ip += NN + 2;
    int* lev     = ip; ip += NN;
    int* tile_of = ip; ip += NN;
    int* tstart  = ip; ip += NN;
    int* tcount  = ip; ip += NN;
    int* done2   = ip; ip += NN + 2;
    int* nt      = ip; ip += 4;
    float* out = (float*)d_out;

    k_init<<<dim3((NN + 2 + 255) / 256), dim3(256), 0, stream>>>(cnt, cur, done2);
    k_root<<<dim3(1), dim3(256), 0, stream>>>(X, state, rootW, rootb, idx, Hb, C, done2);

    k_dep_init<<<dim3(128), dim3(256), 0, stream>>>(parents, depA, jmpA);
    int* dA = depA; int* jA = jmpA; int* dB = depB; int* jB = jmpB;
    for (int it = 0; it < 15; ++it) {
        k_dep_step<<<dim3(128), dim3(256), 0, stream>>>(dA, jA, dB, jB);
        int* tp;
        tp = dA; dA = dB; dB = tp;
        tp = jA; jA = jB; jB = tp;
    }
    k_hist<<<dim3(128), dim3(256), 0, stream>>>(dA, cnt);
    k_scan2<<<dim3(1), dim3(256), 0, stream>>>(cnt, off, tb, nt);
    k_scatter2<<<dim3(128), dim3(256), 0, stream>>>(dA, off, tb, cur, lev, tile_of);
    k_tiles<<<dim3(128), dim3(256), 0, stream>>>(off, tb, tstart, tcount);

    k_tree3<<<dim3(256), dim3(256), 0, stream>>>(X, Wih, Whh, bih, bhh, parents, idx,
                                                 tstart, tcount, nt, tile_of, lev,
                                                 Hb, C, done2);
    k_out<<<dim3(NN + 1), dim3(256), 0, stream>>>(Hb, C, idx, out);
}

// Round 8
// 2253.375 us; speedup vs baseline: 1.3442x; 1.3442x over previous
//
#include <hip/hip_runtime.h>

// TopDownTreeLSTM on MI355X — round 8: R5 fabric + per-tile flags.
// k_gx: Gpre[N,1024] = X·Wih^T + biases (bf16) precomputed at full throughput.
// k_tree4: 256 persistent blocks = 32 groups x 8 col-slices; W_hh K=256 slice
// in LDS. Per tile: prefetch Gpre tile + metadata (shfl, no LDS staging) ->
// wave0 polls <=16 parent-tile counters -> direct LLC->frag H loads ->
// 16 MFMA -> R_s transpose -> contiguous 32-col epilogue/stores (full lines)
// -> release -> per-tile publish (target 8).

#define NN 32768
#define DD 256
#define GP 1024
#define DSTR 16   // done2[] stride in ints (64B lines)

typedef __attribute__((ext_vector_type(8))) short short8;
typedef __attribute__((ext_vector_type(4))) float float4_;

static __device__ __forceinline__ unsigned short f2bf(float f) {
    unsigned u = __builtin_bit_cast(unsigned, f);
    unsigned r = u + 0x7FFFu + ((u >> 16) & 1u);
    return (unsigned short)(r >> 16);
}
static __device__ __forceinline__ float bf2f(unsigned short u) {
    unsigned v = ((unsigned)u) << 16;
    return __builtin_bit_cast(float, v);
}
static __device__ __forceinline__ float sigf(float x) { return 1.0f / (1.0f + __expf(-x)); }
static __device__ __forceinline__ float tanh_(float x) { return 1.0f - 2.0f / (__expf(2.0f * x) + 1.0f); }

__global__ void k_init(int* cnt, int* cur, int* done2) {
    int g = blockIdx.x * 256 + threadIdx.x;
    if (g < NN + 2) { cnt[g] = 0; cur[g] = 0; }
    if (g < (NN + 2) * DSTR) done2[g] = 0;
}

__global__ void k_root(const float* __restrict__ X, const float* __restrict__ state,
                       const float* __restrict__ rootW, const float* __restrict__ rootb,
                       const int* __restrict__ idx,
                       unsigned short* __restrict__ Hb, float* __restrict__ C, int* __restrict__ done2) {
    const int t = threadIdx.x;
    const int row = idx[0];
    const float4_* xr = (const float4_*)(X + (size_t)row * DD);
    const float4_* wr = (const float4_*)(rootW + (size_t)t * DD);
    float acc = rootb[t];
    for (int k = 0; k < DD / 4; ++k) {
        float4_ a = xr[k], b = wr[k];
        acc += a[0] * b[0] + a[1] * b[1] + a[2] * b[2] + a[3] * b[3];
    }
    Hb[t] = f2bf(tanh_(acc));
    C[t] = state[t];
    __syncthreads();
    __threadfence();
    if (t == 0) __hip_atomic_store(&done2[0], 8, __ATOMIC_RELEASE, __HIP_MEMORY_SCOPE_AGENT);
}

__global__ void k_dep_init(const int* __restrict__ parents, int* dep, int* jmp) {
    int i = blockIdx.x * 256 + threadIdx.x;
    if (i >= NN) return;
    dep[i] = (i == 0) ? 0 : 1;
    jmp[i] = (i == 0) ? 0 : parents[i];
}

__global__ void k_dep_step(const int* __restrict__ depA, const int* __restrict__ jmpA,
                           int* __restrict__ depB, int* __restrict__ jmpB) {
    int i = blockIdx.x * 256 + threadIdx.x;
    if (i >= NN) return;
    int j = jmpA[i];
    depB[i] = depA[i] + depA[j];
    jmpB[i] = jmpA[j];
}

__global__ void k_hist(const int* __restrict__ dep, int* cnt) {
    int i = blockIdx.x * 256 + threadIdx.x;
    if (i >= NN) return;
    atomicAdd(&cnt[dep[i]], 1);
}

__global__ void k_scan2(const int* __restrict__ cnt, int* __restrict__ off,
                        int* __restrict__ tb, int* __restrict__ nt) {
    __shared__ int sums[256], tsums[256];
    const int tid = threadIdx.x;
    const int base = tid * 128;
    int s = 0, st = 0;
    for (int k = 0; k < 128; ++k) { int c = cnt[base + k]; s += c; st += (c + 15) >> 4; }
    sums[tid] = s; tsums[tid] = st;
    __syncthreads();
    if (tid == 0) {
        int run = 0, trun = 0;
        for (int t = 0; t < 256; ++t) {
            int a = sums[t]; sums[t] = run; run += a;
            int b = tsums[t]; tsums[t] = trun; trun += b;
        }
    }
    __syncthreads();
    int run = sums[tid], trun = tsums[tid];
    for (int k = 0; k < 128; ++k) {
        off[base + k] = run; tb[base + k] = trun;
        run += cnt[base + k]; trun += (cnt[base + k] + 15) >> 4;
    }
    if (tid == 255) { off[NN] = run; tb[NN] = trun; nt[0] = trun; }
}

__global__ void k_scatter2(const int* __restrict__ dep, const int* __restrict__ off,
                           const int* __restrict__ tb, int* cur,
                           int* __restrict__ lev, int* __restrict__ tile_of) {
    int i = blockIdx.x * 256 + threadIdx.x;
    if (i >= NN) return;
    int d = dep[i];
    int pos = off[d] + atomicAdd(&cur[d], 1);
    lev[pos] = i;
    tile_of[i] = tb[d] + ((pos - off[d]) >> 4);
}

__global__ void k_tiles(const int* __restrict__ off, const int* __restrict__ tb,
                        int* __restrict__ tstart, int* __restrict__ tcount) {
    int d = blockIdx.x * 256 + threadIdx.x;
    if (d >= NN) return;
    int lo = off[d], hi = off[d + 1], t0 = tb[d];
    for (int k = 0; 16 * k < hi - lo; ++k) {
        tstart[t0 + k] = lo + 16 * k;
        tcount[t0 + k] = min(16, hi - lo - 16 * k);
    }
}

// Throughput GEMM: Gpre[n][g] = sum_k X[idx[n]][k]*Wih[g][k] + bih[g] + bhh[g], bf16 out.
__global__ __launch_bounds__(256, 1) void k_gx(
    const float* __restrict__ X, const float* __restrict__ Wih,
    const float* __restrict__ bih, const float* __restrict__ bhh,
    const int* __restrict__ idx, unsigned short* __restrict__ Gp) {
    __shared__ __align__(16) short bw_s[128 * 264];
    __shared__ float bias_s[128];
    const int tid = threadIdx.x;
    const int w = tid >> 6, l = tid & 63;
    const int lanelo = l & 15, quad = l >> 4;

    short8 a[2][8];
    #pragma unroll
    for (int ti = 0; ti < 2; ++ti) {
        int n = (blockIdx.x * 8 + w * 2 + ti) * 16 + lanelo;
        int row = idx[n];
        const float* xp = X + (size_t)row * DD + quad * 8;
        #pragma unroll
        for (int ks = 0; ks < 8; ++ks) {
            float4_ x0 = *(const float4_*)(xp + ks * 32);
            float4_ x1 = *(const float4_*)(xp + ks * 32 + 4);
            short8 s;
            s[0] = f2bf(x0[0]); s[1] = f2bf(x0[1]); s[2] = f2bf(x0[2]); s[3] = f2bf(x0[3]);
            s[4] = f2bf(x1[0]); s[5] = f2bf(x1[1]); s[6] = f2bf(x1[2]); s[7] = f2bf(x1[3]);
            a[ti][ks] = s;
        }
    }
    for (int gc = 0; gc < 8; ++gc) {
        __syncthreads();
        for (int e = tid; e < 128 * 64; e += 256) {
            int r = e >> 6, c4 = (e & 63) * 4;
            float4_ b = *(const float4_*)(Wih + (size_t)(gc * 128 + r) * DD + c4);
            unsigned short* pb = (unsigned short*)&bw_s[r * 264 + c4];
            pb[0] = f2bf(b[0]); pb[1] = f2bf(b[1]); pb[2] = f2bf(b[2]); pb[3] = f2bf(b[3]);
        }
        if (tid < 128) bias_s[tid] = bih[gc * 128 + tid] + bhh[gc * 128 + tid];
        __syncthreads();
        #pragma unroll
        for (int ntl = 0; ntl < 8; ++ntl) {
            float4_ acc0 = (float4_){0.f, 0.f, 0.f, 0.f};
            float4_ acc1 = (float4_){0.f, 0.f, 0.f, 0.f};
            #pragma unroll
            for (int ks = 0; ks < 8; ++ks) {
                short8 bf = *(const short8*)&bw_s[(ntl * 16 + lanelo) * 264 + ks * 32 + quad * 8];
                acc0 = __builtin_amdgcn_mfma_f32_16x16x32_bf16(a[0][ks], bf, acc0, 0, 0, 0);
                acc1 = __builtin_amdgcn_mfma_f32_16x16x32_bf16(a[1][ks], bf, acc1, 0, 0, 0);
            }
            float bia = bias_s[ntl * 16 + lanelo];
            int g = gc * 128 + ntl * 16 + lanelo;
            int nb0 = (blockIdx.x * 8 + w * 2) * 16 + quad * 4;
            #pragma unroll
            for (int r = 0; r < 4; ++r) {
                Gp[(size_t)(nb0 + r) * GP + g] = f2bf(acc0[r] + bia);
                Gp[(size_t)(nb0 + 16 + r) * GP + g] = f2bf(acc1[r] + bia);
            }
        }
    }
}

__global__ __launch_bounds__(256, 1) void k_tree4(
    const float* __restrict__ Whh,
    const int* __restrict__ parents,
    const int* __restrict__ tstart, const int* __restrict__ tcount,
    const int* __restrict__ nt_g, const int* __restrict__ tile_of,
    const int* __restrict__ lev,
    const unsigned short* __restrict__ Gp,
    const float* __restrict__ bih, const float* __restrict__ bhh,
    unsigned short* __restrict__ Hb, float* __restrict__ C, int* __restrict__ done2) {

    __shared__ __align__(16) short w_s[128 * 264];   // W_hh slice bf16, K=256
    __shared__ __align__(16) float G_s[16 * 128];    // Gpre tile fp32 (block's 128 gate cols)
    __shared__ __align__(16) float R_s[16 * 132];    // recurrent gate partials
    __shared__ float bias_s[128];

    const int tid = threadIdx.x;
    const int j = blockIdx.x & 7, grp = blockIdx.x >> 3;
    const int w = tid >> 6, l = tid & 63;
    const int lanelo = l & 15, quad = l >> 4;

    // Stage W_hh slice: local row r -> global gate-row (r>>5)*256 + j*32 + (r&31)
    for (int e = tid; e < 128 * 64; e += 256) {
        int r = e >> 6, c4 = (e & 63) * 4;
        int G = ((r >> 5) * 256) + j * 32 + (r & 31);
        float4_ b = *(const float4_*)(Whh + (size_t)G * DD + c4);
        unsigned short* pb = (unsigned short*)&w_s[r * 264 + c4];
        pb[0] = f2bf(b[0]); pb[1] = f2bf(b[1]); pb[2] = f2bf(b[2]); pb[3] = f2bf(b[3]);
    }
    if (tid < 128) {
        int G = ((tid >> 5) * 256) + j * 32 + (tid & 31);
        bias_s[tid] = bih[G] + bhh[G];
    }
    __syncthreads();

    const int NT = nt_g[0];
    for (int t = 1 + grp; t < NT; t += 32) {
        const int base = tstart[t], count = tcount[t];
        // Per-lane metadata (every wave computes the same; L1-served).
        int node = -1, par = 0, ptile = 0;
        if (lanelo < count) {
            node = lev[base + lanelo];
            par = parents[node];
            ptile = tile_of[par];
        }
        // Prewait: Gpre tile -> G_s (no parent dependency).
        {
            int m = tid >> 4, q8 = (tid & 15) * 8;
            int node_m = __shfl(node, (tid >> 4) & 15);  // src lane m in own wave (m<16)
            // NOTE: m is block-wide 0..15; within a wave, lanes cover 4 m values;
            // shfl source lane index m (0..15) is valid in every wave.
            node_m = __shfl(node, m);
            int seg = q8 >> 5, cc = q8 & 31;
            float4_ g01 = (float4_){0.f, 0.f, 0.f, 0.f};
            float4_ g23 = (float4_){0.f, 0.f, 0.f, 0.f};
            if (node_m >= 0) {
                const unsigned short* gp = Gp + (size_t)node_m * GP + seg * 256 + j * 32 + cc;
                short8 gv = *(const short8*)gp;
                g01[0] = bf2f(gv[0]); g01[1] = bf2f(gv[1]); g01[2] = bf2f(gv[2]); g01[3] = bf2f(gv[3]);
                g23[0] = bf2f(gv[4]); g23[1] = bf2f(gv[5]); g23[2] = bf2f(gv[6]); g23[3] = bf2f(gv[7]);
            }
            *(float4_*)&G_s[m * 128 + q8] = g01;
            *(float4_*)&G_s[m * 128 + q8 + 4] = g23;
        }
        // Wave 0 polls the <=16 parent-tile counters; other waves wait at barrier.
        if (w == 0) {
            int ready = (node < 0);
            while (true) {
                if (!ready)
                    ready = (__hip_atomic_load(&done2[(size_t)ptile * DSTR], __ATOMIC_RELAXED,
                                               __HIP_MEMORY_SCOPE_AGENT) >= 8);
                if (__all(ready)) break;
                __builtin_amdgcn_s_sleep(1);
            }
        }
        __syncthreads();
        __builtin_amdgcn_sched_barrier(0);
        __builtin_amdgcn_fence(__ATOMIC_ACQUIRE, "workgroup");
        // Parent C for epilogue pairs (m0, c) and (m0+8, c).
        float cp0 = 0.f, cp1 = 0.f;
        {
            int m0 = tid >> 5, c = tid & 31, col = j * 32 + c;
            int n0 = __shfl(node, m0 & 15), p0 = __shfl(par, m0 & 15);
            int n1 = __shfl(node, (m0 + 8) & 15), p1 = __shfl(par, (m0 + 8) & 15);
            if (n0 >= 0) cp0 = __hip_atomic_load(&C[(size_t)p0 * DD + col],
                                                 __ATOMIC_RELAXED, __HIP_MEMORY_SCOPE_AGENT);
            if (n1 >= 0) cp1 = __hip_atomic_load(&C[(size_t)p1 * DD + col],
                                                 __ATOMIC_RELAXED, __HIP_MEMORY_SCOPE_AGENT);
        }
        // h A-fragments: direct coherent 16B/lane loads into MFMA layout.
        short8 ah[8];
        const unsigned long long* Hb64 = (const unsigned long long*)Hb;
        #pragma unroll
        for (int ks = 0; ks < 8; ++ks) {
            unsigned long long q0 = 0ull, q1 = 0ull;
            if (node >= 0) {
                size_t b8 = (size_t)par * 64 + ks * 8 + quad * 2;
                q0 = __hip_atomic_load(&Hb64[b8], __ATOMIC_RELAXED, __HIP_MEMORY_SCOPE_AGENT);
                q1 = __hip_atomic_load(&Hb64[b8 + 1], __ATOMIC_RELAXED, __HIP_MEMORY_SCOPE_AGENT);
            }
            union { unsigned long long q[2]; short8 s; } u;
            u.q[0] = q0; u.q[1] = q1;
            ah[ks] = u.s;
        }
        // M=16 K=256 MFMA -> R_s (m = quad*4+r, local gate-col = ntl*16+lanelo).
        {
            #pragma unroll
            for (int ti = 0; ti < 2; ++ti) {
                int ntl = w * 2 + ti;
                float4_ acc = (float4_){0.f, 0.f, 0.f, 0.f};
                #pragma unroll
                for (int ks = 0; ks < 8; ++ks) {
                    short8 bf = *(const short8*)&w_s[(ntl * 16 + lanelo) * 264 + ks * 32 + quad * 8];
                    acc = __builtin_amdgcn_mfma_f32_16x16x32_bf16(ah[ks], bf, acc, 0, 0, 0);
                }
                #pragma unroll
                for (int r = 0; r < 4; ++r)
                    R_s[(quad * 4 + r) * 132 + ntl * 16 + lanelo] = acc[r];
            }
        }
        __syncthreads();
        // Elementwise LSTM, contiguous 32-col stores (full cache lines).
        {
            int m0 = tid >> 5, c = tid & 31, col = j * 32 + c;
            #pragma unroll
            for (int pass = 0; pass < 2; ++pass) {
                int m = m0 + pass * 8;
                int nodem = __shfl(node, m & 15);
                float cp = pass ? cp1 : cp0;
                float ig = R_s[m * 132 + c]      + G_s[m * 128 + c];
                float fg = R_s[m * 132 + 32 + c] + G_s[m * 128 + 32 + c];
                float gg = R_s[m * 132 + 64 + c] + G_s[m * 128 + 64 + c];
                float og = R_s[m * 132 + 96 + c] + G_s[m * 128 + 96 + c];
                float cn = sigf(fg) * cp + sigf(ig) * tanh_(gg);
                float hn = sigf(og) * tanh_(cn);
                unsigned short hs = f2bf(hn);
                unsigned pair = ((unsigned)hs) |
                                (((unsigned)(unsigned short)__shfl_down((int)hs, 1)) << 16);
                if (nodem >= 0) {
                    __hip_atomic_store(&C[(size_t)nodem * DD + col], cn,
                                       __ATOMIC_RELAXED, __HIP_MEMORY_SCOPE_AGENT);
                    if ((c & 1) == 0)
                        __hip_atomic_store(&((unsigned*)Hb)[(size_t)nodem * 128 + (col >> 1)],
                                           pair, __ATOMIC_RELAXED, __HIP_MEMORY_SCOPE_AGENT);
                }
            }
        }
        // Publish this tile immediately.
        __builtin_amdgcn_fence(__ATOMIC_RELEASE, "workgroup");
        __syncthreads();
        if (tid == 0)
            __hip_atomic_fetch_add(&done2[(size_t)t * DSTR], 1,
                                   __ATOMIC_RELAXED, __HIP_MEMORY_SCOPE_AGENT);
    }
}

__global__ void k_out(const unsigned short* __restrict__ Hb, const float* __restrict__ C,
                      const int* __restrict__ idx, float* __restrict__ out) {
    const int b = blockIdx.x, t = threadIdx.x;
    if (b < NN) {
        int drow = idx[b];
        out[512 + (size_t)drow * DD + t] = bf2f(Hb[(size_t)b * DD + t]);
    } else {
        out[t] = C[t];
        out[DD + t] = bf2f(Hb[t]);
    }
}

extern "C" void kernel_launch(void* const* d_in, const int* in_sizes, int n_in,
                              void* d_out, int out_size, void* d_ws, size_t ws_size,
                              hipStream_t stream) {
    const float* X     = (const float*)d_in[0];
    const float* state = (const float*)d_in[1];
    const float* rootW = (const float*)d_in[2];
    const float* rootb = (const float*)d_in[3];
    const float* Wih   = (const float*)d_in[4];
    const float* Whh   = (const float*)d_in[5];
    const float* bih   = (const float*)d_in[6];
    const float* bhh   = (const float*)d_in[7];
    const int* parents = (const int*)d_in[8];
    const int* idx     = (const int*)d_in[9];

    float* C           = (float*)d_ws;                                   // 32 MiB
    unsigned short* Hb = (unsigned short*)(C + (size_t)NN * DD);         // 16 MiB
    unsigned short* Gp = Hb + (size_t)NN * DD;                           // 64 MiB
    int* ip            = (int*)(Gp + (size_t)NN * GP);
    int* depA    = ip; ip += NN;
    int* jmpA    = ip; ip += NN;
    int* depB    = ip; ip += NN;
    int* jmpB    = ip; ip += NN;
    int* cnt     = ip; ip += NN + 2;
    int* off     = ip; ip += NN + 2;
    int* tb      = ip; ip += NN + 2;
    int* cur     = ip; ip += NN + 2;
    int* lev     = ip; ip += NN;
    int* tile_of = ip; ip += NN;
    int* tstart  = ip; ip += NN;
    int* tcount  = ip; ip += NN;
    int* done2   = ip; ip += (NN + 2) * DSTR;
    int* nt      = ip; ip += 4;
    float* out = (float*)d_out;

    k_init<<<dim3(((NN + 2) * DSTR + 255) / 256), dim3(256), 0, stream>>>(cnt, cur, done2);
    k_root<<<dim3(1), dim3(256), 0, stream>>>(X, state, rootW, rootb, idx, Hb, C, done2);

    k_dep_init<<<dim3(128), dim3(256), 0, stream>>>(parents, depA, jmpA);
    int* dA = depA; int* jA = jmpA; int* dB = depB; int* jB = jmpB;
    for (int it = 0; it < 15; ++it) {
        k_dep_step<<<dim3(128), dim3(256), 0, stream>>>(dA, jA, dB, jB);
        int* tp;
        tp = dA; dA = dB; dB = tp;
        tp = jA; jA = jB; jB = tp;
    }
    k_hist<<<dim3(128), dim3(256), 0, stream>>>(dA, cnt);
    k_scan2<<<dim3(1), dim3(256), 0, stream>>>(cnt, off, tb, nt);
    k_scatter2<<<dim3(128), dim3(256), 0, stream>>>(dA, off, tb, cur, lev, tile_of);
    k_tiles<<<dim3(128), dim3(256), 0, stream>>>(off, tb, tstart, tcount);

    k_gx<<<dim3(256), dim3(256), 0, stream>>>(X, Wih, bih, bhh, idx, Gp);
    k_tree4<<<dim3(256), dim3(256), 0, stream>>>(Whh, parents, tstart, tcount, nt, tile_of,
                                                 lev, Gp, bih, bhh, Hb, C, done2);
    k_out<<<dim3(NN + 1), dim3(256), 0, stream>>>(Hb, C, idx, out);
}